// Round 3
// baseline (883.232 us; speedup 1.0000x reference)
//
#include <hip/hip_runtime.h>
#include <hip/hip_bf16.h>
#include <stdint.h>

#define B_TOTAL 262144
#define TB 64
#define SLOT 16384          // 64 rows * 128 cols * 2B
#define BUF1 81920          // second bank: 5 slots
#define LDS_BYTES 163840    // 160 KiB
#define HEAD_W 204800       // bf16 weight elements per head in d_ws

typedef short v8s __attribute__((ext_vector_type(8)));
typedef float v4f __attribute__((ext_vector_type(4)));

union Frag { uint4 q; uint32_t d[4]; v8s v; };

__device__ __forceinline__ uint32_t pack2(float a, float b) {
    union { __hip_bfloat162 h; uint32_t u; } p;
    p.h = __float22bfloat162_rn(make_float2(a, b));
    return p.u;
}

// LDS element [row][k] (bf16) at row*256 + ((k>>3) ^ (row&15))*16 + (k&7)*2

struct KParams {
    const float* x; const float* u; const float* mix; const float* P;
    const float* mb[6];
    const float* tb[6];
    const float* Wout[2];
    const float* bout[2];
    const unsigned short* wbf;
    float* out;
};

struct PrepParams { const float* src[12]; unsigned short* dst; };

__global__ __launch_bounds__(256) void prep_kernel(PrepParams pp) {
    const int ends[12] = {16384,81920,98304,163840,172032,204800,
                          221184,286720,303104,368640,376832,409600};
    int gi = (blockIdx.x * 256 + threadIdx.x) * 4;
    if (gi >= 409600) return;
    int s = 0;
    #pragma unroll
    for (int i = 0; i < 12; ++i) { if (gi >= ends[i]) s = i + 1; }
    int base = (s == 0) ? 0 : ends[s - 1];
    const float4 f = *(const float4*)(pp.src[s] + (gi - base));
    *(uint2*)(pp.dst + gi) = make_uint2(pack2(f.x, f.y), pack2(f.z, f.w));
}

__device__ __forceinline__ void stage_xu(char* lds, const float* x, const float* u,
                                         int rowBase, int tid)
{
    for (int G = tid; G < 1024; G += 512) {
        const int row = G >> 4;
        const int gg  = G & 15;
        const int grow = rowBase + row;
        float4 fa, fb;
        if (gg < 12) {
            const float* s2 = x + grow * 96 + gg * 8;
            fa = *(const float4*)s2; fb = *(const float4*)(s2 + 4);
        } else {
            const float* s2 = u + grow * 32 + (gg - 12) * 8;
            fa = *(const float4*)s2; fb = *(const float4*)(s2 + 4);
        }
        *(uint4*)(lds + row * 256 + ((gg ^ (row & 15)) << 4)) =
            make_uint4(pack2(fa.x, fa.y), pack2(fa.z, fa.w),
                       pack2(fb.x, fb.y), pack2(fb.z, fb.w));
    }
}

// 8 waves, wave = 16-col group (N=128) or (colgroup, row-half) (N=64 final).
// MFMA: A = weight frag (m = output col), B = activation frag (n = batch row).
// Accumulator per lane: batch row bt*16+(lane&15), output cols obase+(lane>>4)*4+r.
template<bool SHARED_IN, int N>
__device__ __forceinline__ void layer_fwd(char* lds, int inOff, int outOff,
        const unsigned short* W, const float* mbias, const float* tbias,
        float c0, const float* cP, int lane, int wave,
        const float* Wout, float* pgrid)
{
    constexpr bool FINAL = (N == 64);
    constexpr int NBT = FINAL ? 2 : 4;
    const int l15  = lane & 15;
    const int quad = lane >> 4;
    const int colBase = FINAL ? ((wave >> 1) << 4) : (wave << 4);
    const int btBase  = FINAL ? ((wave & 1) << 1) : 0;

    v4f acc[5][NBT];
    #pragma unroll
    for (int s = 0; s < 5; ++s)
        #pragma unroll
        for (int bt = 0; bt < NBT; ++bt)
            acc[s][bt] = (v4f){0.f, 0.f, 0.f, 0.f};

    const unsigned short* wRow = W + (colBase + l15) * 128 + quad * 8;

    #pragma unroll
    for (int ks = 0; ks < 4; ++ks) {
        Frag xS[NBT];
        const int gg = ks * 4 + quad;
        if constexpr (SHARED_IN) {
            #pragma unroll
            for (int bt = 0; bt < NBT; ++bt) {
                const int row = (btBase + bt) * 16 + l15;
                xS[bt].q = *(const uint4*)(lds + inOff + row * 256 + ((gg ^ (row & 15)) << 4));
            }
        }
        #pragma unroll
        for (int s = 0; s < 5; ++s) {
            Frag xF[NBT];
            if constexpr (!SHARED_IN) {
                #pragma unroll
                for (int bt = 0; bt < NBT; ++bt) {
                    const int row = (btBase + bt) * 16 + l15;
                    xF[bt].q = *(const uint4*)(lds + inOff + s * SLOT + row * 256
                                               + ((gg ^ (row & 15)) << 4));
                }
            }
            Frag wF;
            wF.q = *(const uint4*)(wRow + s * (N * 128) + ks * 32);
            #pragma unroll
            for (int bt = 0; bt < NBT; ++bt)
                acc[s][bt] = __builtin_amdgcn_mfma_f32_16x16x32_bf16(
                    wF.v, (SHARED_IN ? xS[bt].v : xF[bt].v), acc[s][bt], 0, 0, 0);
        }
    }

    const int obase = colBase + quad * 4;
    const float4 mB = *(const float4*)(mbias + obase);
    float4 tB[4];
    #pragma unroll
    for (int s = 0; s < 4; ++s)
        tB[s] = *(const float4*)(tbias + s * N + obase);

    if constexpr (!FINAL) {
        #pragma unroll
        for (int bt = 0; bt < 4; ++bt) {
            const int row = bt * 16 + l15;
            char* ab = lds + outOff + row * 256 + (((obase >> 3) ^ (row & 15)) << 4)
                       + ((obase & 7) << 1);
            float vr[4];
            vr[0] = c0 * (acc[0][bt][0] + mB.x);
            vr[1] = c0 * (acc[0][bt][1] + mB.y);
            vr[2] = c0 * (acc[0][bt][2] + mB.z);
            vr[3] = c0 * (acc[0][bt][3] + mB.w);
            uint2 tw[4];
            #pragma unroll
            for (int s = 0; s < 4; ++s) {
                float t0 = acc[s + 1][bt][0] + tB[s].x;
                float t1 = acc[s + 1][bt][1] + tB[s].y;
                float t2 = acc[s + 1][bt][2] + tB[s].z;
                float t3 = acc[s + 1][bt][3] + tB[s].w;
                vr[0] = fmaf(cP[s], t0, vr[0]);
                vr[1] = fmaf(cP[s], t1, vr[1]);
                vr[2] = fmaf(cP[s], t2, vr[2]);
                vr[3] = fmaf(cP[s], t3, vr[3]);
                tw[s] = make_uint2(pack2(fmaxf(t0, 0.f), fmaxf(t1, 0.f)),
                                   pack2(fmaxf(t2, 0.f), fmaxf(t3, 0.f)));
            }
            *(uint2*)ab = make_uint2(pack2(fmaxf(vr[0], 0.f), fmaxf(vr[1], 0.f)),
                                     pack2(fmaxf(vr[2], 0.f), fmaxf(vr[3], 0.f)));
            #pragma unroll
            for (int s = 0; s < 4; ++s)
                *(uint2*)(ab + (s + 1) * SLOT) = tw[s];
        }
    } else {
        const float4 wo = *(const float4*)(Wout + obase);
        float psum[NBT];
        #pragma unroll
        for (int j = 0; j < NBT; ++j) {
            float vr[4];
            vr[0] = c0 * (acc[0][j][0] + mB.x);
            vr[1] = c0 * (acc[0][j][1] + mB.y);
            vr[2] = c0 * (acc[0][j][2] + mB.z);
            vr[3] = c0 * (acc[0][j][3] + mB.w);
            #pragma unroll
            for (int s = 0; s < 4; ++s) {
                vr[0] = fmaf(cP[s], acc[s + 1][j][0] + tB[s].x, vr[0]);
                vr[1] = fmaf(cP[s], acc[s + 1][j][1] + tB[s].y, vr[1]);
                vr[2] = fmaf(cP[s], acc[s + 1][j][2] + tB[s].z, vr[2]);
                vr[3] = fmaf(cP[s], acc[s + 1][j][3] + tB[s].w, vr[3]);
            }
            float pp = fmaxf(vr[0], 0.f) * wo.x + fmaxf(vr[1], 0.f) * wo.y
                     + fmaxf(vr[2], 0.f) * wo.z + fmaxf(vr[3], 0.f) * wo.w;
            pp += __shfl_xor(pp, 16);
            pp += __shfl_xor(pp, 32);
            psum[j] = pp;
        }
        if (lane < 16) {
            #pragma unroll
            for (int j = 0; j < NBT; ++j)
                pgrid[(wave >> 1) * 64 + (btBase + j) * 16 + lane] = psum[j];
        }
    }
}

extern "C" __global__ __launch_bounds__(512, 2)
void critic_kernel(KParams p)
{
    extern __shared__ char lds[];
    const int tid  = threadIdx.x;
    const int lane = tid & 63;
    const int wave = tid >> 6;
    const int rowBase = blockIdx.x * TB;

    const float m  = p.mix[0];
    const float c0 = 1.f - m;
    float cP[4];
    #pragma unroll
    for (int k = 0; k < 4; ++k) cP[k] = m * p.P[k];

    stage_xu(lds, p.x, p.u, rowBase, tid);

    #pragma unroll 1
    for (int head = 0; head < 2; ++head) {
        __syncthreads();
        const unsigned short* wb = p.wbf + head * HEAD_W;
        const int hb = head * 3;

        // L1: xu (BUF0.slot0, shared) -> BUF1 (5 relu'd streams)
        layer_fwd<true, 128>(lds, 0, BUF1, wb, p.mb[hb + 0], p.tb[hb + 0],
                             c0, cP, lane, wave, nullptr, nullptr);
        __syncthreads();
        // L2: BUF1 -> BUF0 (overwrites xu slot)
        layer_fwd<false, 128>(lds, BUF1, 0, wb + 81920, p.mb[hb + 1], p.tb[hb + 1],
                              c0, cP, lane, wave, nullptr, nullptr);
        __syncthreads();
        // L3 + L4: BUF0 -> register combine -> dot(Wout) -> pgrid (in BUF1)
        layer_fwd<false, 64>(lds, 0, 0, wb + 163840, p.mb[hb + 2], p.tb[hb + 2],
                             c0, cP, lane, wave, p.Wout[head], (float*)(lds + BUF1));
        __syncthreads();

        if (tid < 64) {
            const float* pg = (const float*)(lds + BUF1);
            p.out[head * B_TOTAL + rowBase + tid] =
                p.bout[head][0] + pg[tid] + pg[64 + tid] + pg[128 + tid] + pg[192 + tid];
        }
        if (head == 0)
            stage_xu(lds, p.x, p.u, rowBase, tid);   // L2 overwrote xu; restage for head 1
    }
}

extern "C" void kernel_launch(void* const* d_in, const int* in_sizes, int n_in,
                              void* d_out, int out_size, void* d_ws, size_t ws_size,
                              hipStream_t stream)
{
    (void)in_sizes; (void)n_in; (void)out_size; (void)ws_size;

    PrepParams pp;
    const int sidx[12] = {4, 20, 6, 22, 8, 24, 12, 26, 14, 28, 16, 30};
    for (int i = 0; i < 12; ++i) pp.src[i] = (const float*)d_in[sidx[i]];
    pp.dst = (unsigned short*)d_ws;

    KParams kp;
    kp.x = (const float*)d_in[0];  kp.u = (const float*)d_in[1];
    kp.mix = (const float*)d_in[2]; kp.P = (const float*)d_in[3];
    const int mbi[6] = {5, 7, 9, 13, 15, 17};
    const int tbi[6] = {21, 23, 25, 27, 29, 31};
    for (int i = 0; i < 6; ++i) {
        kp.mb[i] = (const float*)d_in[mbi[i]];
        kp.tb[i] = (const float*)d_in[tbi[i]];
    }
    kp.Wout[0] = (const float*)d_in[10]; kp.Wout[1] = (const float*)d_in[18];
    kp.bout[0] = (const float*)d_in[11]; kp.bout[1] = (const float*)d_in[19];
    kp.wbf = (const unsigned short*)d_ws;
    kp.out = (float*)d_out;

    (void)hipFuncSetAttribute((const void*)critic_kernel,
                              hipFuncAttributeMaxDynamicSharedMemorySize, LDS_BYTES);

    hipLaunchKernelGGL(prep_kernel, dim3(400), dim3(256), 0, stream, pp);
    hipLaunchKernelGGL(critic_kernel, dim3(4096), dim3(512), LDS_BYTES, stream, kp);
}

// Round 4
// 846.881 us; speedup vs baseline: 1.0429x; 1.0429x over previous
//
#include <hip/hip_runtime.h>
#include <hip/hip_bf16.h>
#include <stdint.h>

#define B_TOTAL 262144
#define TB 64
#define SLOT 16384          // 64 rows * 128 cols * 2B
#define BUF1 81920          // second bank: 5 slots
#define LDS_BYTES 163840    // 160 KiB
#define HEAD_W 204800       // bf16 weight elements per head in d_ws

typedef short v8s __attribute__((ext_vector_type(8)));
typedef float v4f __attribute__((ext_vector_type(4)));

union Frag { uint4 q; uint32_t d[4]; v8s v; };

__device__ __forceinline__ uint32_t pack2(float a, float b) {
    union { __hip_bfloat162 h; uint32_t u; } p;
    p.h = __float22bfloat162_rn(make_float2(a, b));
    return p.u;
}

// LDS element [row][k] (bf16) at row*256 + ((k>>3) ^ (row&15))*16 + (k&7)*2

struct KParams {
    const float* x; const float* u; const float* mix; const float* P;
    const float* mb[6];
    const float* tb[6];
    const float* Wout[2];
    const float* bout[2];
    const unsigned short* wbf;
    float* out;
};

struct PrepParams { const float* src[12]; unsigned short* dst; };

__global__ __launch_bounds__(256) void prep_kernel(PrepParams pp) {
    const int ends[12] = {16384,81920,98304,163840,172032,204800,
                          221184,286720,303104,368640,376832,409600};
    int gi = (blockIdx.x * 256 + threadIdx.x) * 4;
    if (gi >= 409600) return;
    int s = 0;
    #pragma unroll
    for (int i = 0; i < 12; ++i) { if (gi >= ends[i]) s = i + 1; }
    int base = (s == 0) ? 0 : ends[s - 1];
    const float4 f = *(const float4*)(pp.src[s] + (gi - base));
    *(uint2*)(pp.dst + gi) = make_uint2(pack2(f.x, f.y), pack2(f.z, f.w));
}

__device__ __forceinline__ void stage_xu(char* lds, const float* x, const float* u,
                                         int rowBase, int tid)
{
    for (int G = tid; G < 1024; G += 512) {
        const int row = G >> 4;
        const int gg  = G & 15;
        const int grow = rowBase + row;
        float4 fa, fb;
        if (gg < 12) {
            const float* s2 = x + grow * 96 + gg * 8;
            fa = *(const float4*)s2; fb = *(const float4*)(s2 + 4);
        } else {
            const float* s2 = u + grow * 32 + (gg - 12) * 8;
            fa = *(const float4*)s2; fb = *(const float4*)(s2 + 4);
        }
        *(uint4*)(lds + row * 256 + ((gg ^ (row & 15)) << 4)) =
            make_uint4(pack2(fa.x, fa.y), pack2(fa.z, fa.w),
                       pack2(fb.x, fb.y), pack2(fb.z, fb.w));
    }
}

// Pre-loaded per-phase state: all 20 weight fragments + biases, in registers.
// Issued BEFORE the phase barrier so L2 latency overlaps barrier + prior epilogue.
struct WPre { Frag w[20]; float4 mB; float4 tB[4]; };

template<int N>
__device__ __forceinline__ WPre preload(const unsigned short* W,
        const float* mbias, const float* tbias, int lane, int wave)
{
    WPre r;
    const int l15  = lane & 15;
    const int quad = lane >> 4;
    const int colBase = (N == 64) ? ((wave >> 1) << 4) : (wave << 4);
    const unsigned short* wRow = W + (colBase + l15) * 128 + quad * 8;
    #pragma unroll
    for (int s = 0; s < 5; ++s)
        #pragma unroll
        for (int ks = 0; ks < 4; ++ks)
            r.w[s * 4 + ks].q = *(const uint4*)(wRow + s * (N * 128) + ks * 32);
    const int obase = colBase + quad * 4;
    r.mB = *(const float4*)(mbias + obase);
    #pragma unroll
    for (int s = 0; s < 4; ++s)
        r.tB[s] = *(const float4*)(tbias + s * N + obase);
    return r;
}

// 8 waves. N=128: wave = 16-col group, 4 row-tiles. N=64 (final): wave =
// (colgroup, row-half), fused combine + Wout dot -> pgrid.
// MFMA: A = weight frag (m = out col), B = activation frag (n = batch row).
// Acc per lane: batch row bt*16+(lane&15), out cols obase+(lane>>4)*4+r.
template<bool SHARED_IN, int N>
__device__ __forceinline__ void compute(char* lds, int inOff, int outOff,
        const WPre& wp, float c0, const float* cP, int lane, int wave,
        const float* Wout, float* pgrid)
{
    constexpr bool FINAL = (N == 64);
    constexpr int NBT = FINAL ? 2 : 4;
    const int l15  = lane & 15;
    const int quad = lane >> 4;
    const int colBase = FINAL ? ((wave >> 1) << 4) : (wave << 4);
    const int btBase  = FINAL ? ((wave & 1) << 1) : 0;

    v4f acc[5][NBT];
    #pragma unroll
    for (int s = 0; s < 5; ++s)
        #pragma unroll
        for (int bt = 0; bt < NBT; ++bt)
            acc[s][bt] = (v4f){0.f, 0.f, 0.f, 0.f};

    #pragma unroll
    for (int ks = 0; ks < 4; ++ks) {
        const int gg = ks * 4 + quad;
        Frag xS[NBT];
        if constexpr (SHARED_IN) {
            #pragma unroll
            for (int bt = 0; bt < NBT; ++bt) {
                const int row = (btBase + bt) * 16 + l15;
                xS[bt].q = *(const uint4*)(lds + inOff + row * 256 + ((gg ^ (row & 15)) << 4));
            }
        }
        #pragma unroll
        for (int s = 0; s < 5; ++s) {
            Frag xF[NBT];
            if constexpr (!SHARED_IN) {
                #pragma unroll
                for (int bt = 0; bt < NBT; ++bt) {
                    const int row = (btBase + bt) * 16 + l15;
                    xF[bt].q = *(const uint4*)(lds + inOff + s * SLOT + row * 256
                                               + ((gg ^ (row & 15)) << 4));
                }
            }
            #pragma unroll
            for (int bt = 0; bt < NBT; ++bt)
                acc[s][bt] = __builtin_amdgcn_mfma_f32_16x16x32_bf16(
                    wp.w[s * 4 + ks].v, (SHARED_IN ? xS[bt].v : xF[bt].v),
                    acc[s][bt], 0, 0, 0);
        }
    }

    const int obase = colBase + quad * 4;

    if constexpr (!FINAL) {
        #pragma unroll
        for (int bt = 0; bt < 4; ++bt) {
            const int row = bt * 16 + l15;
            char* ab = lds + outOff + row * 256 + (((obase >> 3) ^ (row & 15)) << 4)
                       + ((obase & 7) << 1);
            float vr[4];
            vr[0] = c0 * (acc[0][bt][0] + wp.mB.x);
            vr[1] = c0 * (acc[0][bt][1] + wp.mB.y);
            vr[2] = c0 * (acc[0][bt][2] + wp.mB.z);
            vr[3] = c0 * (acc[0][bt][3] + wp.mB.w);
            uint2 tw[4];
            #pragma unroll
            for (int s = 0; s < 4; ++s) {
                float t0 = acc[s + 1][bt][0] + wp.tB[s].x;
                float t1 = acc[s + 1][bt][1] + wp.tB[s].y;
                float t2 = acc[s + 1][bt][2] + wp.tB[s].z;
                float t3 = acc[s + 1][bt][3] + wp.tB[s].w;
                vr[0] = fmaf(cP[s], t0, vr[0]);
                vr[1] = fmaf(cP[s], t1, vr[1]);
                vr[2] = fmaf(cP[s], t2, vr[2]);
                vr[3] = fmaf(cP[s], t3, vr[3]);
                tw[s] = make_uint2(pack2(fmaxf(t0, 0.f), fmaxf(t1, 0.f)),
                                   pack2(fmaxf(t2, 0.f), fmaxf(t3, 0.f)));
            }
            *(uint2*)ab = make_uint2(pack2(fmaxf(vr[0], 0.f), fmaxf(vr[1], 0.f)),
                                     pack2(fmaxf(vr[2], 0.f), fmaxf(vr[3], 0.f)));
            #pragma unroll
            for (int s = 0; s < 4; ++s)
                *(uint2*)(ab + (s + 1) * SLOT) = tw[s];
        }
    } else {
        const float4 wo = *(const float4*)(Wout + obase);
        float psum[NBT];
        #pragma unroll
        for (int j = 0; j < NBT; ++j) {
            float vr[4];
            vr[0] = c0 * (acc[0][j][0] + wp.mB.x);
            vr[1] = c0 * (acc[0][j][1] + wp.mB.y);
            vr[2] = c0 * (acc[0][j][2] + wp.mB.z);
            vr[3] = c0 * (acc[0][j][3] + wp.mB.w);
            #pragma unroll
            for (int s = 0; s < 4; ++s) {
                vr[0] = fmaf(cP[s], acc[s + 1][j][0] + wp.tB[s].x, vr[0]);
                vr[1] = fmaf(cP[s], acc[s + 1][j][1] + wp.tB[s].y, vr[1]);
                vr[2] = fmaf(cP[s], acc[s + 1][j][2] + wp.tB[s].z, vr[2]);
                vr[3] = fmaf(cP[s], acc[s + 1][j][3] + wp.tB[s].w, vr[3]);
            }
            float pp = fmaxf(vr[0], 0.f) * wo.x + fmaxf(vr[1], 0.f) * wo.y
                     + fmaxf(vr[2], 0.f) * wo.z + fmaxf(vr[3], 0.f) * wo.w;
            pp += __shfl_xor(pp, 16);
            pp += __shfl_xor(pp, 32);
            psum[j] = pp;
        }
        if (lane < 16) {
            #pragma unroll
            for (int j = 0; j < NBT; ++j)
                pgrid[(wave >> 1) * 64 + (btBase + j) * 16 + lane] = psum[j];
        }
    }
}

extern "C" __global__ __launch_bounds__(512, 2)
void critic_kernel(KParams p)
{
    extern __shared__ char lds[];
    const int tid  = threadIdx.x;
    const int lane = tid & 63;
    const int wave = tid >> 6;
    const int rowBase = blockIdx.x * TB;

    const float m  = p.mix[0];
    const float c0 = 1.f - m;
    float cP[4];
    #pragma unroll
    for (int k = 0; k < 4; ++k) cP[k] = m * p.P[k];

    stage_xu(lds, p.x, p.u, rowBase, tid);

    #pragma unroll 1
    for (int head = 0; head < 2; ++head) {
        const unsigned short* wb = p.wbf + head * HEAD_W;
        const int hb = head * 3;

        // Preload phase weights BEFORE each barrier: L2 latency overlaps
        // the barrier wait + previous phase's epilogue.
        WPre w1 = preload<128>(wb, p.mb[hb + 0], p.tb[hb + 0], lane, wave);
        __syncthreads();
        // L1: xu (BUF0.slot0, shared) -> BUF1 (5 relu'd streams)
        compute<true, 128>(lds, 0, BUF1, w1, c0, cP, lane, wave, nullptr, nullptr);

        WPre w2 = preload<128>(wb + 81920, p.mb[hb + 1], p.tb[hb + 1], lane, wave);
        __syncthreads();
        // L2: BUF1 -> BUF0 (overwrites xu slot)
        compute<false, 128>(lds, BUF1, 0, w2, c0, cP, lane, wave, nullptr, nullptr);

        WPre w3 = preload<64>(wb + 163840, p.mb[hb + 2], p.tb[hb + 2], lane, wave);
        __syncthreads();
        // L3 + L4: BUF0 -> register combine -> dot(Wout) -> pgrid (in BUF1)
        compute<false, 64>(lds, 0, 0, w3, c0, cP, lane, wave,
                           p.Wout[head], (float*)(lds + BUF1));
        __syncthreads();

        if (tid < 64) {
            const float* pg = (const float*)(lds + BUF1);
            p.out[head * B_TOTAL + rowBase + tid] =
                p.bout[head][0] + pg[tid] + pg[64 + tid] + pg[128 + tid] + pg[192 + tid];
        }
        if (head == 0) {
            stage_xu(lds, p.x, p.u, rowBase, tid);   // L2 overwrote xu; restage
        }
    }
}

extern "C" void kernel_launch(void* const* d_in, const int* in_sizes, int n_in,
                              void* d_out, int out_size, void* d_ws, size_t ws_size,
                              hipStream_t stream)
{
    (void)in_sizes; (void)n_in; (void)out_size; (void)ws_size;

    PrepParams pp;
    const int sidx[12] = {4, 20, 6, 22, 8, 24, 12, 26, 14, 28, 16, 30};
    for (int i = 0; i < 12; ++i) pp.src[i] = (const float*)d_in[sidx[i]];
    pp.dst = (unsigned short*)d_ws;

    KParams kp;
    kp.x = (const float*)d_in[0];  kp.u = (const float*)d_in[1];
    kp.mix = (const float*)d_in[2]; kp.P = (const float*)d_in[3];
    const int mbi[6] = {5, 7, 9, 13, 15, 17};
    const int tbi[6] = {21, 23, 25, 27, 29, 31};
    for (int i = 0; i < 6; ++i) {
        kp.mb[i] = (const float*)d_in[mbi[i]];
        kp.tb[i] = (const float*)d_in[tbi[i]];
    }
    kp.Wout[0] = (const float*)d_in[10]; kp.Wout[1] = (const float*)d_in[18];
    kp.bout[0] = (const float*)d_in[11]; kp.bout[1] = (const float*)d_in[19];
    kp.wbf = (const unsigned short*)d_ws;
    kp.out = (float*)d_out;

    (void)hipFuncSetAttribute((const void*)critic_kernel,
                              hipFuncAttributeMaxDynamicSharedMemorySize, LDS_BYTES);

    hipLaunchKernelGGL(prep_kernel, dim3(400), dim3(256), 0, stream, pp);
    hipLaunchKernelGGL(critic_kernel, dim3(4096), dim3(512), LDS_BYTES, stream, kp);
}